// Round 1
// baseline (59.219 us; speedup 1.0000x reference)
//
#include <hip/hip_runtime.h>

// PopulationAttention: out = (Q K^T / sqrt(64)) @ (V * x)
// No softmax => associativity: out = Q @ M / 8, M = K^T @ (V*x)  (64x64 per head)
// B=4, H=16, N=2048, D=64  -> BH=64 batched heads.

#define BH 64
#define NROWS 2048
#define DIM 64
#define QROWS 128  // rows of Q per block in stage B

// ---------------- Stage A: partial[bh][chunk] = sum_{m in chunk} K[m]^T (V[m]*x[m]) ----------------
__global__ __launch_bounds__(256) void popattn_kv(
    const float* __restrict__ K, const float* __restrict__ V,
    const float* __restrict__ x, float* __restrict__ partial, int nchunk) {
  const int ch = blockIdx.x;
  const int bh = blockIdx.y;
  const int rows = NROWS / nchunk;
  const int m0base = ch * rows;
  const float* Kp = K + (size_t)bh * (NROWS * DIM);
  const float* Vp = V + (size_t)bh * (NROWS * DIM);
  const float* xp = x + (size_t)(bh >> 4) * NROWS;  // x is [B,1,N,1], b = bh/16

  __shared__ float sK[16][DIM];
  __shared__ float sV[16][DIM];

  const int t = threadIdx.x;
  const int lr = t >> 4;          // load row 0..15
  const int lc = (t & 15) << 2;   // load col (float4)
  const int ti = (t >> 4) << 2;   // 4x4 tile row base (0..60)
  const int tj = (t & 15) << 2;   // 4x4 tile col base

  float acc[4][4];
#pragma unroll
  for (int i = 0; i < 4; ++i)
#pragma unroll
    for (int j = 0; j < 4; ++j) acc[i][j] = 0.f;

  for (int m0 = m0base; m0 < m0base + rows; m0 += 16) {
    const float4 kv = *(const float4*)(Kp + (size_t)(m0 + lr) * DIM + lc);
    const float4 vv = *(const float4*)(Vp + (size_t)(m0 + lr) * DIM + lc);
    const float xv = xp[m0 + lr];
    __syncthreads();  // protect previous iteration's reads
    *(float4*)&sK[lr][lc] = kv;
    float4 vs;
    vs.x = vv.x * xv; vs.y = vv.y * xv; vs.z = vv.z * xv; vs.w = vv.w * xv;
    *(float4*)&sV[lr][lc] = vs;
    __syncthreads();
#pragma unroll
    for (int mm = 0; mm < 16; ++mm) {
      const float4 ka = *(const float4*)&sK[mm][ti];
      const float4 va = *(const float4*)&sV[mm][tj];
      const float kk[4] = {ka.x, ka.y, ka.z, ka.w};
      const float vw[4] = {va.x, va.y, va.z, va.w};
#pragma unroll
      for (int ii = 0; ii < 4; ++ii)
#pragma unroll
        for (int jj = 0; jj < 4; ++jj) acc[ii][jj] += kk[ii] * vw[jj];
    }
  }

  float* Pp = partial + ((size_t)bh * nchunk + ch) * (DIM * DIM);
#pragma unroll
  for (int ii = 0; ii < 4; ++ii) {
    float4 o;
    o.x = acc[ii][0]; o.y = acc[ii][1]; o.z = acc[ii][2]; o.w = acc[ii][3];
    *(float4*)(Pp + (size_t)(ti + ii) * DIM + tj) = o;
  }
}

// ---------------- Stage B: out[bh] = Q[bh] @ (sum_c partial[bh][c]) / 8 ----------------
__global__ __launch_bounds__(256) void popattn_qm(
    const float* __restrict__ Q, const float* __restrict__ partial,
    float* __restrict__ out, int nchunk) {
  const int ch = blockIdx.x;  // 0..15
  const int bh = blockIdx.y;
  const int row0 = ch * QROWS;
  const float* Qp = Q + (size_t)bh * (NROWS * DIM) + (size_t)row0 * DIM;
  float* Op = out + (size_t)bh * (NROWS * DIM) + (size_t)row0 * DIM;
  const float* Pp = partial + (size_t)bh * nchunk * (DIM * DIM);

  __shared__ float sM[DIM * DIM];      // 16 KB
  __shared__ float sQ[QROWS * 65];     // 33.25 KB, stride 65 kills bank conflicts

  const int t = threadIdx.x;

  // Reduce partials into sM (fixed order -> deterministic), fold 1/sqrt(64)=0.125
#pragma unroll
  for (int e = 0; e < 4; ++e) {
    const int off = e * 1024 + t * 4;
    float sx = 0.f, sy = 0.f, sz = 0.f, sw = 0.f;
    for (int c = 0; c < nchunk; ++c) {
      const float4 p = *(const float4*)(Pp + (size_t)c * (DIM * DIM) + off);
      sx += p.x; sy += p.y; sz += p.z; sw += p.w;
    }
    float4 o;
    o.x = sx * 0.125f; o.y = sy * 0.125f; o.z = sz * 0.125f; o.w = sw * 0.125f;
    *(float4*)&sM[off] = o;
  }

  // Stage Q chunk into LDS (scalar writes due to stride-65 padding)
#pragma unroll
  for (int p = 0; p < 8; ++p) {
    const int r = p * 16 + (t >> 4);
    const int c = (t & 15) << 2;
    const float4 q = *(const float4*)(Qp + (size_t)r * DIM + c);
    float* dst = &sQ[r * 65 + c];
    dst[0] = q.x; dst[1] = q.y; dst[2] = q.z; dst[3] = q.w;
  }
  __syncthreads();

  const int tr = (t >> 4) * 8;   // 8 rows per thread
  const int tj = (t & 15) << 2;  // 4 cols per thread
  float acc[8][4];
#pragma unroll
  for (int rr = 0; rr < 8; ++rr)
#pragma unroll
    for (int jj = 0; jj < 4; ++jj) acc[rr][jj] = 0.f;

#pragma unroll 8
  for (int i = 0; i < DIM; ++i) {
    const float4 mv = *(const float4*)&sM[i * DIM + tj];
    const float mm[4] = {mv.x, mv.y, mv.z, mv.w};
#pragma unroll
    for (int rr = 0; rr < 8; ++rr) {
      const float q = sQ[(tr + rr) * 65 + i];
      acc[rr][0] += q * mm[0];
      acc[rr][1] += q * mm[1];
      acc[rr][2] += q * mm[2];
      acc[rr][3] += q * mm[3];
    }
  }

#pragma unroll
  for (int rr = 0; rr < 8; ++rr) {
    float4 o;
    o.x = acc[rr][0]; o.y = acc[rr][1]; o.z = acc[rr][2]; o.w = acc[rr][3];
    *(float4*)(Op + (size_t)(tr + rr) * DIM + tj) = o;
  }
}

extern "C" void kernel_launch(void* const* d_in, const int* in_sizes, int n_in,
                              void* d_out, int out_size, void* d_ws, size_t ws_size,
                              hipStream_t stream) {
  const float* Q = (const float*)d_in[0];
  const float* K = (const float*)d_in[1];
  const float* V = (const float*)d_in[2];
  const float* x = (const float*)d_in[3];
  float* out = (float*)d_out;
  float* partial = (float*)d_ws;

  // Workspace: BH * nchunk * 64*64 floats. Clamp nchunk to fit ws_size.
  int nchunk = 8;
  while (nchunk > 1 &&
         (size_t)BH * nchunk * DIM * DIM * sizeof(float) > ws_size)
    nchunk >>= 1;

  dim3 blk(256);
  dim3 gA(nchunk, BH);
  popattn_kv<<<gA, blk, 0, stream>>>(K, V, x, partial, nchunk);

  dim3 gB(NROWS / QROWS, BH);
  popattn_qm<<<gB, blk, 0, stream>>>(Q, partial, out, nchunk);
}

// Round 2
// 44.226 us; speedup vs baseline: 1.3390x; 1.3390x over previous
//
#include <hip/hip_runtime.h>

// PopulationAttention: out = (Q K^T / sqrt(64)) @ (V * x)
// No softmax => associativity: out = Q @ M / 8, M = K^T @ (V*x)  (64x64 per head)
// B=4, H=16, N=2048, D=64  -> BH=64 batched heads.

#define BH 64
#define NROWS 2048
#define DIM 64

// ---------------- Stage A: partial[bh][chunk] = sum_{m in chunk} K[m]^T (V[m]*x[m]) ----------------
__global__ __launch_bounds__(256) void popattn_kv(
    const float* __restrict__ K, const float* __restrict__ V,
    const float* __restrict__ x, float* __restrict__ partial, int nchunk) {
  const int ch = blockIdx.x;
  const int bh = blockIdx.y;
  const int rows = NROWS / nchunk;
  const int m0base = ch * rows;
  const float* Kp = K + (size_t)bh * (NROWS * DIM);
  const float* Vp = V + (size_t)bh * (NROWS * DIM);
  const float* xp = x + (size_t)(bh >> 4) * NROWS;  // x is [B,1,N,1], b = bh/16

  __shared__ float sK[32][DIM];  // 8 KB
  __shared__ float sV[32][DIM];  // 8 KB

  const int t = threadIdx.x;
  const int lr = t >> 4;          // load row 0..15 (and +16)
  const int lc = (t & 15) << 2;   // load col (float4)
  const int ti = (t >> 4) << 2;   // 4x4 tile row base (0..60)
  const int tj = (t & 15) << 2;   // 4x4 tile col base

  float acc[4][4];
#pragma unroll
  for (int i = 0; i < 4; ++i)
#pragma unroll
    for (int j = 0; j < 4; ++j) acc[i][j] = 0.f;

  for (int m0 = m0base; m0 < m0base + rows; m0 += 32) {
    const float4 kv0 = *(const float4*)(Kp + (size_t)(m0 + lr) * DIM + lc);
    const float4 kv1 = *(const float4*)(Kp + (size_t)(m0 + 16 + lr) * DIM + lc);
    const float4 vv0 = *(const float4*)(Vp + (size_t)(m0 + lr) * DIM + lc);
    const float4 vv1 = *(const float4*)(Vp + (size_t)(m0 + 16 + lr) * DIM + lc);
    const float xv0 = xp[m0 + lr];
    const float xv1 = xp[m0 + 16 + lr];
    __syncthreads();  // protect previous iteration's reads
    *(float4*)&sK[lr][lc] = kv0;
    *(float4*)&sK[lr + 16][lc] = kv1;
    float4 vs;
    vs.x = vv0.x * xv0; vs.y = vv0.y * xv0; vs.z = vv0.z * xv0; vs.w = vv0.w * xv0;
    *(float4*)&sV[lr][lc] = vs;
    vs.x = vv1.x * xv1; vs.y = vv1.y * xv1; vs.z = vv1.z * xv1; vs.w = vv1.w * xv1;
    *(float4*)&sV[lr + 16][lc] = vs;
    __syncthreads();
#pragma unroll
    for (int mm = 0; mm < 32; ++mm) {
      const float4 ka = *(const float4*)&sK[mm][ti];
      const float4 va = *(const float4*)&sV[mm][tj];
      const float kk[4] = {ka.x, ka.y, ka.z, ka.w};
      const float vw[4] = {va.x, va.y, va.z, va.w};
#pragma unroll
      for (int ii = 0; ii < 4; ++ii)
#pragma unroll
        for (int jj = 0; jj < 4; ++jj) acc[ii][jj] += kk[ii] * vw[jj];
    }
  }

  float* Pp = partial + ((size_t)bh * nchunk + ch) * (DIM * DIM);
#pragma unroll
  for (int ii = 0; ii < 4; ++ii) {
    float4 o;
    o.x = acc[ii][0]; o.y = acc[ii][1]; o.z = acc[ii][2]; o.w = acc[ii][3];
    *(float4*)(Pp + (size_t)(ti + ii) * DIM + tj) = o;
  }
}

// ---------------- Stage A2: M[bh] = (sum_c partial[bh][c]) * 0.125 ----------------
__global__ __launch_bounds__(256) void popattn_red(
    const float* __restrict__ partial, float* __restrict__ M, int nchunk) {
  const int e = blockIdx.x;   // 0..3 quarter of the 64x64 matrix
  const int bh = blockIdx.y;
  const int off = e * 1024 + threadIdx.x * 4;
  const float* Pp = partial + (size_t)bh * nchunk * (DIM * DIM);
  float sx = 0.f, sy = 0.f, sz = 0.f, sw = 0.f;
#pragma unroll 4
  for (int c = 0; c < nchunk; ++c) {
    const float4 p = *(const float4*)(Pp + (size_t)c * (DIM * DIM) + off);
    sx += p.x; sy += p.y; sz += p.z; sw += p.w;
  }
  float4 o;
  o.x = sx * 0.125f; o.y = sy * 0.125f; o.z = sz * 0.125f; o.w = sw * 0.125f;
  *(float4*)(M + (size_t)bh * (DIM * DIM) + off) = o;
}

// ---------------- Stage B: out[bh] = Q[bh] @ M[bh] ----------------
// 64 Q-rows per block; per thread: rows (r0, r0+32), cols (c4..c4+3, c4+32..c4+35).
__global__ __launch_bounds__(256) void popattn_qm(
    const float* __restrict__ Q, const float* __restrict__ M,
    float* __restrict__ out) {
  const int ch = blockIdx.x;  // 0..31
  const int bh = blockIdx.y;
  const int row0 = ch * 64;
  const float* Qp = Q + (size_t)bh * (NROWS * DIM) + (size_t)row0 * DIM;
  float* Op = out + (size_t)bh * (NROWS * DIM) + (size_t)row0 * DIM;

  __shared__ float sM[DIM * DIM];  // 16 KB

  const int t = threadIdx.x;
  {
    const float* Mp = M + (size_t)bh * (DIM * DIM);
#pragma unroll
    for (int i = 0; i < 4; ++i) {
      const int off = i * 1024 + t * 4;
      *(float4*)&sM[off] = *(const float4*)(Mp + off);
    }
  }
  __syncthreads();

  const int r0 = t >> 3;        // 0..31 (also owns r0+32)
  const int c4 = (t & 7) * 4;   // 0..28 (also owns c4+32)

  float a00 = 0.f, a01 = 0.f, a02 = 0.f, a03 = 0.f;  // row r0,   cols c4..
  float a04 = 0.f, a05 = 0.f, a06 = 0.f, a07 = 0.f;  // row r0,   cols c4+32..
  float a10 = 0.f, a11 = 0.f, a12 = 0.f, a13 = 0.f;  // row r0+32, cols c4..
  float a14 = 0.f, a15 = 0.f, a16 = 0.f, a17 = 0.f;  // row r0+32, cols c4+32..

#pragma unroll
  for (int kg = 0; kg < 16; ++kg) {
    const float4 qa = *(const float4*)(Qp + (size_t)r0 * DIM + kg * 4);
    const float4 qb = *(const float4*)(Qp + (size_t)(r0 + 32) * DIM + kg * 4);
    const float qav[4] = {qa.x, qa.y, qa.z, qa.w};
    const float qbv[4] = {qb.x, qb.y, qb.z, qb.w};
#pragma unroll
    for (int dk = 0; dk < 4; ++dk) {
      const int k = kg * 4 + dk;
      const float4 m0 = *(const float4*)&sM[k * DIM + c4];
      const float4 m1 = *(const float4*)&sM[k * DIM + c4 + 32];
      const float q0 = qav[dk], q1 = qbv[dk];
      a00 += q0 * m0.x; a01 += q0 * m0.y; a02 += q0 * m0.z; a03 += q0 * m0.w;
      a04 += q0 * m1.x; a05 += q0 * m1.y; a06 += q0 * m1.z; a07 += q0 * m1.w;
      a10 += q1 * m0.x; a11 += q1 * m0.y; a12 += q1 * m0.z; a13 += q1 * m0.w;
      a14 += q1 * m1.x; a15 += q1 * m1.y; a16 += q1 * m1.z; a17 += q1 * m1.w;
    }
  }

  float4 o;
  o.x = a00; o.y = a01; o.z = a02; o.w = a03;
  *(float4*)(Op + (size_t)r0 * DIM + c4) = o;
  o.x = a04; o.y = a05; o.z = a06; o.w = a07;
  *(float4*)(Op + (size_t)r0 * DIM + c4 + 32) = o;
  o.x = a10; o.y = a11; o.z = a12; o.w = a13;
  *(float4*)(Op + (size_t)(r0 + 32) * DIM + c4) = o;
  o.x = a14; o.y = a15; o.z = a16; o.w = a17;
  *(float4*)(Op + (size_t)(r0 + 32) * DIM + c4 + 32) = o;
}

extern "C" void kernel_launch(void* const* d_in, const int* in_sizes, int n_in,
                              void* d_out, int out_size, void* d_ws, size_t ws_size,
                              hipStream_t stream) {
  const float* Q = (const float*)d_in[0];
  const float* K = (const float*)d_in[1];
  const float* V = (const float*)d_in[2];
  const float* x = (const float*)d_in[3];
  float* out = (float*)d_out;
  float* partial = (float*)d_ws;

  // Workspace: BH*nchunk*4096 floats of partials + BH*4096 floats for M.
  int nchunk = 16;
  while (nchunk > 1 &&
         ((size_t)BH * nchunk * DIM * DIM + (size_t)BH * DIM * DIM) * sizeof(float) > ws_size)
    nchunk >>= 1;
  float* Mbuf = partial + (size_t)BH * nchunk * DIM * DIM;

  dim3 blk(256);
  popattn_kv<<<dim3(nchunk, BH), blk, 0, stream>>>(K, V, x, partial, nchunk);
  popattn_red<<<dim3(4, BH), blk, 0, stream>>>(partial, Mbuf, nchunk);
  popattn_qm<<<dim3(NROWS / 64, BH), blk, 0, stream>>>(Q, Mbuf, out);
}